// Round 2
// baseline (217.069 us; speedup 1.0000x reference)
//
#include <hip/hip_runtime.h>

// VQ-VAE vector quantizer, fp32 VALU implementation, round 2.
// Theory: round-1 was LDS-instr-bound (b32 E-reads + conflicts). This version:
//   - 8 points x 8 codes per thread (codes strided by 16 -> conflict-free b128)
//   - all LDS traffic as ds_read_b128 / ds_write_b128
//   - E chunk stays code-major [c][68] (pad breaks bank aliasing), no transpose
//   - hsq = 0.5*||e||^2 precomputed once for all 1024 codes
//   - register prefetch of next E chunk across compute
// inputs: d_in[0] = inputs [16,64,64,64] NCHW fp32, d_in[1] = embedding [1024,64] fp32
// out (fp32 concat): [ loss(1) | quantized NCHW (4194304) | indices as float (65536) ]

#define DIMS   64
#define HW     4096      // 64*64
#define NPTS   65536
#define NCODES 1024
#define NP     128       // points per block
#define KC     128       // codes per chunk
#define NCH    8         // 1024/128
#define QOFF   1
#define IOFF   (1 + 16 * DIMS * HW)
#define ESTR   68        // Es stride: 64+4 keeps float4 alignment, banks = col*4 (2-way max)

__device__ __forceinline__ float f4c(const float4& v, int r) {
    switch (r) { case 0: return v.x; case 1: return v.y; case 2: return v.z; default: return v.w; }
}

__launch_bounds__(256, 2)
__global__ void vq_main(const float* __restrict__ in, const float* __restrict__ emb,
                        float* __restrict__ out)
{
    // LDS floats: Xs[64][128]=8192 | Es[128][68]=8704 | hsq[1024] -> 17920 f = 71680 B, 2 blk/CU
    __shared__ float smem[8192 + KC * ESTR + NCODES];
    float* Xs  = smem;
    float* Es  = smem + 8192;
    float* hsq = smem + 8192 + KC * ESTR;

    const int tid = threadIdx.x;
    const int col = tid & 15;       // 16 code-columns; thread's codes = col + 16*j
    const int row = tid >> 4;       // 16 point-rows
    const int p0  = row * 8;

    const int n0  = blockIdx.x * NP;
    const int b   = n0 >> 12;       // 128 | 4096 -> never crosses a batch
    const int off = n0 & 4095;

    // ---- stage X tile: NCHW is [d][p]-contiguous per batch -> identity b128 copy
    const float4* inb = (const float4*)(in + (size_t)b * (DIMS * HW) + off);
    #pragma unroll
    for (int i = 0; i < 8; ++i) {
        int idx = tid + i * 256;            // 0..2047 float4s
        int d = idx >> 5, p4 = idx & 31;
        *(float4*)&Xs[d * 128 + p4 * 4] = inb[d * (HW / 4) + p4];
    }

    // ---- hsq[k] = 0.5*||e_k||^2 for all 1024 codes (256 wave-instrs of global b128, L2-hot)
    #pragma unroll
    for (int t = 0; t < 4; ++t) {
        int k = tid + t * 256;
        const float4* er = (const float4*)(emb + (size_t)k * DIMS);
        float s = 0.f;
        #pragma unroll
        for (int i = 0; i < 16; ++i) {
            float4 v = er[i];
            s = fmaf(v.x, v.x, s); s = fmaf(v.y, v.y, s);
            s = fmaf(v.z, v.z, s); s = fmaf(v.w, v.w, s);
        }
        hsq[k] = 0.5f * s;
    }

    // ---- prefetch E chunk 0 into registers
    float4 pf[8];
    {
        const float4* eb = (const float4*)emb;
        #pragma unroll
        for (int i = 0; i < 8; ++i) pf[i] = eb[tid + i * 256];
    }

    float minv[8]; int mini[8];
    #pragma unroll
    for (int i = 0; i < 8; ++i) { minv[i] = 3.0e38f; mini[i] = 0; }

    for (int ch = 0; ch < NCH; ++ch) {
        __syncthreads();                    // previous chunk's Es readers done (also covers Xs/hsq writes)
        #pragma unroll
        for (int i = 0; i < 8; ++i) {       // 2048 float4s -> Es[c][dg*4], all b128 writes
            int idx = tid + i * 256;
            int c = idx >> 4, dg = idx & 15;
            *(float4*)&Es[c * ESTR + dg * 4] = pf[i];
        }
        if (ch + 1 < NCH) {                 // prefetch next chunk while this one is computed
            const float4* eb = (const float4*)(emb + (size_t)(ch + 1) * KC * DIMS);
            #pragma unroll
            for (int i = 0; i < 8; ++i) pf[i] = eb[tid + i * 256];
        }
        __syncthreads();

        float acc[8][8];                    // [point][code] dot accumulators
        #pragma unroll
        for (int i = 0; i < 8; ++i)
            #pragma unroll
            for (int j = 0; j < 8; ++j) acc[i][j] = 0.f;

        #pragma unroll 2
        for (int d4 = 0; d4 < 16; ++d4) {   // 4 dims per step, all-b128 LDS
            float4 xa[4], xb[4];
            #pragma unroll
            for (int r = 0; r < 4; ++r) {   // 16-way broadcast across cols
                xa[r] = *(const float4*)&Xs[(d4 * 4 + r) * 128 + p0];
                xb[r] = *(const float4*)&Xs[(d4 * 4 + r) * 128 + p0 + 4];
            }
            #pragma unroll
            for (int jh = 0; jh < 2; ++jh) {            // split codes 2x4 to cap live regs
                float4 e4[4];
                #pragma unroll
                for (int j4 = 0; j4 < 4; ++j4)
                    e4[j4] = *(const float4*)&Es[(col + 16 * (jh * 4 + j4)) * ESTR + d4 * 4];
                #pragma unroll
                for (int r = 0; r < 4; ++r) {
                    float x0 = f4c(xa[r], 0), x1 = f4c(xa[r], 1), x2 = f4c(xa[r], 2), x3 = f4c(xa[r], 3);
                    float x4 = f4c(xb[r], 0), x5 = f4c(xb[r], 1), x6 = f4c(xb[r], 2), x7 = f4c(xb[r], 3);
                    #pragma unroll
                    for (int j4 = 0; j4 < 4; ++j4) {
                        float ev = f4c(e4[j4], r);
                        int j = jh * 4 + j4;
                        acc[0][j] = fmaf(x0, ev, acc[0][j]);
                        acc[1][j] = fmaf(x1, ev, acc[1][j]);
                        acc[2][j] = fmaf(x2, ev, acc[2][j]);
                        acc[3][j] = fmaf(x3, ev, acc[3][j]);
                        acc[4][j] = fmaf(x4, ev, acc[4][j]);
                        acc[5][j] = fmaf(x5, ev, acc[5][j]);
                        acc[6][j] = fmaf(x6, ev, acc[6][j]);
                        acc[7][j] = fmaf(x7, ev, acc[7][j]);
                    }
                }
            }
        }

        // ---- running argmin of (0.5||e||^2 - x.e)  [= dist/2, same ordering incl. ties]
        const int kb = ch * KC;
        #pragma unroll
        for (int j = 0; j < 8; ++j) {
            int k = kb + col + 16 * j;      // ascending in (ch, j) for fixed thread -> first-min kept
            float h = hsq[k];
            #pragma unroll
            for (int i = 0; i < 8; ++i) {
                float s = h - acc[i][j];
                if (s < minv[i]) { minv[i] = s; mini[i] = k; }
            }
        }
    }

    // ---- cross-column argmin reduce (reuse Es region; stride 17 -> conflict-free)
    __syncthreads();
    float* redv  = Es;                              // [128][17]
    int*   redi  = (int*)(Es + 2176);               // [128][17]
    float* lossb = Es + 4352;                       // [128]
    #pragma unroll
    for (int i = 0; i < 8; ++i) {
        int p = p0 + i;
        redv[p * 17 + col] = minv[i];
        redi[p * 17 + col] = mini[i];
    }
    __syncthreads();

    if (tid < NP) {
        const int p = tid;
        float bv = redv[p * 17];
        int   bi = redi[p * 17];
        #pragma unroll
        for (int c = 1; c < 16; ++c) {
            float v  = redv[p * 17 + c];
            int   id = redi[p * 17 + c];
            if (v < bv || (v == bv && id < bi)) { bv = v; bi = id; }
        }
        out[IOFF + n0 + p] = (float)bi;
        const float* e = emb + (size_t)bi * DIMS;   // gather row (L2-resident table)
        float* oq = out + QOFF + (size_t)b * (DIMS * HW) + off + p;
        float lsum = 0.f;
        #pragma unroll 8
        for (int c = 0; c < DIMS; ++c) {
            float ev = e[c];
            float xv = Xs[c * 128 + p];
            float df = ev - xv;
            lsum = fmaf(df, df, lsum);
            oq[c * HW] = ev;                        // coalesced across threads
        }
        lossb[p] = lsum;
    }
    __syncthreads();
    if (tid == 0) {
        float s = 0.f;
        #pragma unroll 8
        for (int i = 0; i < NP; ++i) s += lossb[i];
        atomicAdd(out, s * (0.25f / (float)(16 * DIMS * HW)));
    }
}

extern "C" void kernel_launch(void* const* d_in, const int* in_sizes, int n_in,
                              void* d_out, int out_size, void* d_ws, size_t ws_size,
                              hipStream_t stream) {
    const float* in  = (const float*)d_in[0];
    const float* emb = (const float*)d_in[1];
    float* out = (float*)d_out;
    (void)d_ws; (void)ws_size; (void)in_sizes; (void)n_in; (void)out_size;

    hipMemsetAsync(d_out, 0, sizeof(float), stream);  // loss accumulated via atomics
    vq_main<<<NPTS / NP, 256, 0, stream>>>(in, emb, out);
}

// Round 3
// 165.815 us; speedup vs baseline: 1.3091x; 1.3091x over previous
//
#include <hip/hip_runtime.h>

// VQ-VAE vector quantizer, round 3: split-bf16 MFMA.
// dot(x,e) = xh.eh + xh.el + xl.eh accumulated in fp32 MFMA acc (3x mfma_f32_16x16x32_bf16).
// argmin on v = 0.5||e||^2 - dot (same ordering as true distance). Per-point top-1 + runner-up
// VALUE tracked; if gap < EPSGAP the block rescans that point exactly in fp32 (rare: ~0.1/block).
// Layouts: X/E tiles in LDS as [row][16B-unit u ^ (row&7)] XOR swizzle -> conflict-free b128,
// A/B frags: lane m=lane&15 -> row, quad=lane>>4, k = quad*8+j (verified bf16 16x16x32 layout).
// out (fp32 concat): [ loss(1) | quantized NCHW (4194304) | indices as float (65536) ]

#define DIMS   64
#define HW     4096
#define NPTS   65536
#define NCODES 1024
#define NPB    128            // points per block
#define QOFF   1
#define IOFF   (1 + NPTS * DIMS)
#define EPSGAP 3.0e-3f

typedef unsigned int uint;
typedef unsigned short ushort;
typedef __attribute__((ext_vector_type(8))) short short8;
typedef __attribute__((ext_vector_type(4))) float f32x4;

__device__ __forceinline__ ushort bf16_rne(float f) {
    uint u = __float_as_uint(f);
    uint r = u + 0x7FFFu + ((u >> 16) & 1u);
    return (ushort)(r >> 16);
}
__device__ __forceinline__ float bf16f(ushort h) { return __uint_as_float(((uint)h) << 16); }

// ---- pre-kernel: emb fp32 -> ws {Eh[1024][64] bf16, El[1024][64] bf16, hsq[1024] f32}
__global__ void vq_prep(const float* __restrict__ emb, ushort* __restrict__ Eh,
                        ushort* __restrict__ El, float* __restrict__ hsq)
{
    const int t = blockIdx.x * 256 + threadIdx.x;      // 0..4095
    const float4* e4 = (const float4*)emb;
    #pragma unroll
    for (int i = 0; i < 4; ++i) {
        int idx = t + i * 4096;                        // 0..16383 float4 units
        float4 v = e4[idx];
        ushort h0 = bf16_rne(v.x), h1 = bf16_rne(v.y), h2 = bf16_rne(v.z), h3 = bf16_rne(v.w);
        ushort l0 = bf16_rne(v.x - bf16f(h0)), l1 = bf16_rne(v.y - bf16f(h1));
        ushort l2 = bf16_rne(v.z - bf16f(h2)), l3 = bf16_rne(v.w - bf16f(h3));
        uint2 hp, lp;
        hp.x = (uint)h0 | ((uint)h1 << 16); hp.y = (uint)h2 | ((uint)h3 << 16);
        lp.x = (uint)l0 | ((uint)l1 << 16); lp.y = (uint)l2 | ((uint)l3 << 16);
        *(uint2*)(Eh + (size_t)idx * 4) = hp;
        *(uint2*)(El + (size_t)idx * 4) = lp;
    }
    if (t < NCODES) {
        const float* r = emb + (size_t)t * DIMS;
        float s = 0.f;
        for (int d = 0; d < DIMS; ++d) s = fmaf(r[d], r[d], s);
        hsq[t] = 0.5f * s;
    }
}

__launch_bounds__(256, 2)
__global__ void vq_main(const float* __restrict__ in, const float* __restrict__ emb,
                        const ushort* __restrict__ Ehw, const ushort* __restrict__ Elw,
                        const float* __restrict__ hsqw, float* __restrict__ out)
{
    // [0,16384) XH | [16384,32768) XL | [32768,65536) E double-buffer (buf: H@+0, L@+8192)
    __shared__ __align__(16) unsigned char smem[65536];

    const int tid = threadIdx.x;
    const int n0 = blockIdx.x * NPB;
    const int b = n0 >> 12, off = n0 & 4095;           // 128 | 4096: never crosses a batch
    const float* xbase = in + (size_t)b * (DIMS * HW) + off;

    // ---- stage X: p = tid&127, dim-half = tid>>7; global loads coalesced over p
    {
        const int p = tid & 127, dh = tid >> 7;
        const float* xp = xbase + p;
        #pragma unroll
        for (int g = 0; g < 4; ++g) {
            const int u = dh * 4 + g;                  // 16B-unit = 8 dims
            uint hp[4], lp[4];
            #pragma unroll
            for (int j2 = 0; j2 < 4; ++j2) {
                float a = xp[(u * 8 + j2 * 2 + 0) * HW];
                float c = xp[(u * 8 + j2 * 2 + 1) * HW];
                ushort ha = bf16_rne(a), hc = bf16_rne(c);
                ushort la = bf16_rne(a - bf16f(ha)), lc = bf16_rne(c - bf16f(hc));
                hp[j2] = (uint)ha | ((uint)hc << 16);
                lp[j2] = (uint)la | ((uint)lc << 16);
            }
            const int slot = (u ^ (p & 7)) * 16;       // XOR swizzle, no pad, 16B aligned
            *(uint4*)(smem + p * 128 + slot) = make_uint4(hp[0], hp[1], hp[2], hp[3]);
            *(uint4*)(smem + 16384 + p * 128 + slot) = make_uint4(lp[0], lp[1], lp[2], lp[3]);
        }
    }
    __syncthreads();

    const int lane = tid & 63, w = tid >> 6;
    const int m = lane & 15, quad = lane >> 4;

    // ---- A fragments (2 point-tiles x 2 k-steps, hi+lo) held in regs for whole kernel
    short8 Ah[2][2], Al[2][2];
    #pragma unroll
    for (int pt = 0; pt < 2; ++pt) {
        const int p = w * 32 + pt * 16 + m;
        #pragma unroll
        for (int ks = 0; ks < 2; ++ks) {
            const int u = ks * 4 + quad;
            const int a = p * 128 + ((u ^ (p & 7)) * 16);
            Ah[pt][ks] = *(const short8*)(smem + a);
            Al[pt][ks] = *(const short8*)(smem + 16384 + a);
        }
    }

    float v1s[8], v2s[8]; int i1s[8];                  // 8 point-states per lane
    #pragma unroll
    for (int s = 0; s < 8; ++s) { v1s[s] = 1e30f; v2s[s] = 1e30f; i1s[s] = 0; }

    // ---- stage E chunk 0 (64 codes) into buf0
    #pragma unroll
    for (int t = 0; t < 2; ++t) {
        int idx = tid + t * 256, c = idx >> 3, u = idx & 7;
        uint4 vh = *(const uint4*)(Ehw + (size_t)c * 64 + u * 8);
        uint4 vl = *(const uint4*)(Elw + (size_t)c * 64 + u * 8);
        int d = c * 128 + ((u ^ (c & 7)) * 16);
        *(uint4*)(smem + 32768 + d) = vh;
        *(uint4*)(smem + 32768 + 8192 + d) = vl;
    }
    __syncthreads();

    for (int ch = 0; ch < 16; ++ch) {
        const int buf = ch & 1;
        uint4 nh[2], nl[2];
        if (ch < 15) {                                 // prefetch next chunk into regs
            #pragma unroll
            for (int t = 0; t < 2; ++t) {
                int idx = tid + t * 256, c = idx >> 3, u = idx & 7;
                size_t g = ((size_t)((ch + 1) * 64 + c)) * 64 + u * 8;
                nh[t] = *(const uint4*)(Ehw + g);
                nl[t] = *(const uint4*)(Elw + g);
            }
        }
        const unsigned char* EH = smem + 32768 + buf * 16384;
        const unsigned char* EL = EH + 8192;
        const int kb0 = ch * 64;
        float hv[4];
        #pragma unroll
        for (int nt = 0; nt < 4; ++nt) hv[nt] = hsqw[kb0 + nt * 16 + m];

        #pragma unroll
        for (int np = 0; np < 2; ++np) {
            const int ca = np * 32 + m, cb = ca + 16;  // two code-subtiles (pairing for v2)
            short8 BhA[2], BlA[2], BhB[2], BlB[2];
            #pragma unroll
            for (int ks = 0; ks < 2; ++ks) {
                const int u = ks * 4 + quad;
                const int aa = ca * 128 + ((u ^ (ca & 7)) * 16);
                const int ab = cb * 128 + ((u ^ (cb & 7)) * 16);
                BhA[ks] = *(const short8*)(EH + aa);
                BlA[ks] = *(const short8*)(EL + aa);
                BhB[ks] = *(const short8*)(EH + ab);
                BlB[ks] = *(const short8*)(EL + ab);
            }
            const float ha = hv[np * 2], hb = hv[np * 2 + 1];
            const int ka = kb0 + np * 32 + m, kb = ka + 16;
            #pragma unroll
            for (int pt = 0; pt < 2; ++pt) {
                f32x4 aA = {0.f, 0.f, 0.f, 0.f}, aB = {0.f, 0.f, 0.f, 0.f};
                // hh + hl + lh products, two K=32 steps each; two chains for ILP
                aA = __builtin_amdgcn_mfma_f32_16x16x32_bf16(Ah[pt][0], BhA[0], aA, 0, 0, 0);
                aB = __builtin_amdgcn_mfma_f32_16x16x32_bf16(Ah[pt][0], BhB[0], aB, 0, 0, 0);
                aA = __builtin_amdgcn_mfma_f32_16x16x32_bf16(Ah[pt][1], BhA[1], aA, 0, 0, 0);
                aB = __builtin_amdgcn_mfma_f32_16x16x32_bf16(Ah[pt][1], BhB[1], aB, 0, 0, 0);
                aA = __builtin_amdgcn_mfma_f32_16x16x32_bf16(Ah[pt][0], BlA[0], aA, 0, 0, 0);
                aB = __builtin_amdgcn_mfma_f32_16x16x32_bf16(Ah[pt][0], BlB[0], aB, 0, 0, 0);
                aA = __builtin_amdgcn_mfma_f32_16x16x32_bf16(Ah[pt][1], BlA[1], aA, 0, 0, 0);
                aB = __builtin_amdgcn_mfma_f32_16x16x32_bf16(Ah[pt][1], BlB[1], aB, 0, 0, 0);
                aA = __builtin_amdgcn_mfma_f32_16x16x32_bf16(Al[pt][0], BhA[0], aA, 0, 0, 0);
                aB = __builtin_amdgcn_mfma_f32_16x16x32_bf16(Al[pt][0], BhB[0], aB, 0, 0, 0);
                aA = __builtin_amdgcn_mfma_f32_16x16x32_bf16(Al[pt][1], BhA[1], aA, 0, 0, 0);
                aB = __builtin_amdgcn_mfma_f32_16x16x32_bf16(Al[pt][1], BhB[1], aB, 0, 0, 0);
                #pragma unroll
                for (int r = 0; r < 4; ++r) {
                    const int s = pt * 4 + r;
                    float va = ha - aA[r], vb = hb - aB[r];
                    float pm = fminf(va, vb);
                    int ip = (vb < va) ? kb : ka;      // tie -> lower code ka
                    v2s[s] = fminf(v2s[s], fmaxf(pm, v1s[s]));
                    bool c2 = pm < v1s[s];             // strict: tie keeps earlier (lower) idx
                    v1s[s] = fminf(v1s[s], pm);
                    i1s[s] = c2 ? ip : i1s[s];
                }
            }
        }

        if (ch < 15) {                                 // write prefetched chunk to other buf
            unsigned char* nb = smem + 32768 + (buf ^ 1) * 16384;
            #pragma unroll
            for (int t = 0; t < 2; ++t) {
                int idx = tid + t * 256, c = idx >> 3, u = idx & 7;
                int d = c * 128 + ((u ^ (c & 7)) * 16);
                *(uint4*)(nb + d) = nh[t];
                *(uint4*)(nb + 8192 + d) = nl[t];
            }
        }
        __syncthreads();
    }

    // ---- merge states across the 16 columns (xor shuffle within 16-lane groups)
    #pragma unroll
    for (int st = 1; st < 16; st <<= 1) {
        #pragma unroll
        for (int s = 0; s < 8; ++s) {
            float ov1 = __shfl_xor(v1s[s], st);
            float ov2 = __shfl_xor(v2s[s], st);
            int   oi1 = __shfl_xor(i1s[s], st);
            v2s[s] = fminf(fminf(v2s[s], ov2), fmaxf(v1s[s], ov1));
            bool c = (ov1 < v1s[s]) || (ov1 == v1s[s] && oi1 < i1s[s]);
            if (c) i1s[s] = oi1;
            v1s[s] = fminf(v1s[s], ov1);
        }
    }

    // epilogue scratch overlays the (dead) X region
    float* pv1 = (float*)smem;                         // [128]
    int*   pi1 = (int*)(smem + 512);                   // [128]
    float* pv2 = (float*)(smem + 1024);                // [128]
    int*   flg = (int*)(smem + 1536);                  // [128]
    int*   lst = (int*)(smem + 2048);                  // [0]=cnt, entries at +1
    float* rv  = (float*)(smem + 4096);                // [256]
    int*   rk  = (int*)(smem + 5120);                  // [256]
    float* lsb = (float*)(smem + 6144);                // [128]

    if (m == 0) {
        #pragma unroll
        for (int s = 0; s < 8; ++s) {
            int p = w * 32 + (s >> 2) * 16 + quad * 4 + (s & 3);
            pv1[p] = v1s[s]; pi1[p] = i1s[s]; pv2[p] = v2s[s];
        }
    }
    __syncthreads();

    if (tid < NPB) flg[tid] = (pv2[tid] - pv1[tid]) < EPSGAP ? 1 : 0;
    __syncthreads();
    if (tid == 0) {
        int c = 0;
        for (int i = 0; i < NPB; ++i) if (flg[i]) lst[1 + c++] = i;
        lst[0] = c;
    }
    __syncthreads();

    // ---- exact fp32 rescan for near-tie points (rare); whole block per point
    const int cnt = lst[0];
    for (int it = 0; it < cnt; ++it) {
        const int p = lst[1 + it];
        const float* xp = xbase + p;
        const int k0 = tid * 4;                        // 4 codes per thread
        float dot[4] = {0.f, 0.f, 0.f, 0.f};
        for (int d4 = 0; d4 < 16; ++d4) {
            float x0 = xp[(d4 * 4 + 0) * HW], x1 = xp[(d4 * 4 + 1) * HW];
            float x2 = xp[(d4 * 4 + 2) * HW], x3 = xp[(d4 * 4 + 3) * HW];
            #pragma unroll
            for (int j = 0; j < 4; ++j) {
                float4 e = *(const float4*)(emb + (size_t)(k0 + j) * DIMS + d4 * 4);
                dot[j] = fmaf(x0, e.x, dot[j]); dot[j] = fmaf(x1, e.y, dot[j]);
                dot[j] = fmaf(x2, e.z, dot[j]); dot[j] = fmaf(x3, e.w, dot[j]);
            }
        }
        float bv = 1e30f; int bk = 0;
        #pragma unroll
        for (int j = 0; j < 4; ++j) {
            float v = hsqw[k0 + j] - dot[j];
            if (v < bv) { bv = v; bk = k0 + j; }       // ascending j: first-min kept
        }
        rv[tid] = bv; rk[tid] = bk;
        __syncthreads();
        if (tid == 0) {
            float fbv = rv[0]; int fbk = rk[0];
            for (int i = 1; i < 256; ++i)              // ascending tid = ascending k
                if (rv[i] < fbv) { fbv = rv[i]; fbk = rk[i]; }
            pi1[p] = fbk;
        }
        __syncthreads();
    }

    // ---- final: indices, quantized gather-write, loss
    if (tid < NPB) {
        const int p = tid;
        const int bi = pi1[p];
        out[IOFF + n0 + p] = (float)bi;
        const float* e = emb + (size_t)bi * DIMS;
        const float* xp = xbase + p;
        float* oq = out + QOFF + (size_t)b * (DIMS * HW) + off + p;
        float ls = 0.f;
        #pragma unroll 8
        for (int d = 0; d < DIMS; ++d) {
            float ev = e[d];
            float xv = xp[d * HW];
            float df = ev - xv;
            ls = fmaf(df, df, ls);
            oq[d * HW] = ev;                           // coalesced across point-threads
        }
        lsb[p] = ls;
    }
    __syncthreads();
    if (tid == 0) {
        float s = 0.f;
        for (int i = 0; i < NPB; ++i) s += lsb[i];
        atomicAdd(out, s * (0.25f / (float)(NPTS * DIMS)));
    }
}

extern "C" void kernel_launch(void* const* d_in, const int* in_sizes, int n_in,
                              void* d_out, int out_size, void* d_ws, size_t ws_size,
                              hipStream_t stream) {
    const float* in  = (const float*)d_in[0];
    const float* emb = (const float*)d_in[1];
    float* out = (float*)d_out;
    ushort* Eh = (ushort*)d_ws;                        // 131072 B
    ushort* El = (ushort*)((char*)d_ws + 131072);      // 131072 B
    float*  hsq = (float*)((char*)d_ws + 262144);      // 4096 B
    (void)in_sizes; (void)n_in; (void)out_size; (void)ws_size;

    hipMemsetAsync(d_out, 0, sizeof(float), stream);   // loss accumulated via atomics
    vq_prep<<<16, 256, 0, stream>>>(emb, Eh, El, hsq);
    vq_main<<<512, 256, 0, stream>>>(in, emb, Eh, El, hsq, out);
}

// Round 4
// 163.968 us; speedup vs baseline: 1.3238x; 1.0113x over previous
//
#include <hip/hip_runtime.h>

// VQ-VAE vector quantizer, round 4: split-bf16 MFMA, barrier-free K-loop.
// dot(x,e) = xh.eh + xh.el + xl.eh in fp32 MFMA acc (6 mfma_f32_16x16x32_bf16 per 16x16 tile).
// B-fragments load DIRECTLY from global (Eh/El 256KB, L1/L2-hot) -> no E staging, no barriers
// in the K-loop, LDS = X tile only (32 KB). Exact top-2 tracking; near-ties (gap < 1e-3,
// error bound ~1e-4) rescanned exactly in fp32 by one wave per flagged point.
// out (fp32 concat): [ loss(1) | quantized NCHW (4194304) | indices as float (65536) ]

#define DIMS   64
#define HW     4096
#define NPTS   65536
#define NCODES 1024
#define NPB    128
#define QOFF   1
#define IOFF   (1 + NPTS * DIMS)
#define EPSGAP 1.0e-3f

typedef unsigned int uint;
typedef unsigned short ushort;
typedef unsigned long long ull;
typedef __attribute__((ext_vector_type(8))) short short8;
typedef __attribute__((ext_vector_type(4))) float f32x4;

__device__ __forceinline__ ushort bf16_rne(float f) {
    uint u = __float_as_uint(f);
    uint r = u + 0x7FFFu + ((u >> 16) & 1u);
    return (ushort)(r >> 16);
}
__device__ __forceinline__ float bf16f(ushort h) { return __uint_as_float(((uint)h) << 16); }

// ---- prep: emb fp32 -> {Eh, El bf16 [1024][64]}, hsq = 0.5||e||^2, and zero out[0]
__global__ void vq_prep(const float* __restrict__ emb, ushort* __restrict__ Eh,
                        ushort* __restrict__ El, float* __restrict__ hsq,
                        float* __restrict__ out)
{
    const int t = blockIdx.x * 256 + threadIdx.x;      // 0..16383, one float4 each
    if (t == 0) out[0] = 0.f;                          // loss accumulator (atomics later)
    float4 v = ((const float4*)emb)[t];
    ushort h0 = bf16_rne(v.x), h1 = bf16_rne(v.y), h2 = bf16_rne(v.z), h3 = bf16_rne(v.w);
    ushort l0 = bf16_rne(v.x - bf16f(h0)), l1 = bf16_rne(v.y - bf16f(h1));
    ushort l2 = bf16_rne(v.z - bf16f(h2)), l3 = bf16_rne(v.w - bf16f(h3));
    uint2 hp, lp;
    hp.x = (uint)h0 | ((uint)h1 << 16); hp.y = (uint)h2 | ((uint)h3 << 16);
    lp.x = (uint)l0 | ((uint)l1 << 16); lp.y = (uint)l2 | ((uint)l3 << 16);
    *(uint2*)(Eh + (size_t)t * 4) = hp;
    *(uint2*)(El + (size_t)t * 4) = lp;
    if (t < NCODES) {
        const float4* r = (const float4*)(emb + (size_t)t * DIMS);
        float s = 0.f;
        #pragma unroll
        for (int i = 0; i < 16; ++i) {
            float4 e = r[i];
            s = fmaf(e.x, e.x, s); s = fmaf(e.y, e.y, s);
            s = fmaf(e.z, e.z, s); s = fmaf(e.w, e.w, s);
        }
        hsq[t] = 0.5f * s;
    }
}

__launch_bounds__(256, 2)
__global__ void vq_main(const float* __restrict__ in, const float* __restrict__ emb,
                        const ushort* __restrict__ Ehw, const ushort* __restrict__ Elw,
                        const float* __restrict__ hsqw, float* __restrict__ out)
{
    // 32 KB: XH [0,16K) | XL [16K,32K); dead after A-frag load -> reused by epilogue
    __shared__ __align__(16) unsigned char smem[32768];

    const int tid = threadIdx.x;
    const int n0 = blockIdx.x * NPB;
    const int b = n0 >> 12, off = n0 & 4095;           // 128 | 4096: never crosses a batch
    const float* xbase = in + (size_t)b * (DIMS * HW) + off;

    // ---- stage X hi/lo bf16 into LDS [p][16B-unit u ^ (p&7)] (coalesced over p)
    {
        const int p = tid & 127, dh = tid >> 7;
        const float* xp = xbase + p;
        #pragma unroll
        for (int g = 0; g < 4; ++g) {
            const int u = dh * 4 + g;                  // 16B-unit = 8 dims
            uint hp[4], lp[4];
            #pragma unroll
            for (int j2 = 0; j2 < 4; ++j2) {
                float a = xp[(u * 8 + j2 * 2 + 0) * HW];
                float c = xp[(u * 8 + j2 * 2 + 1) * HW];
                ushort ha = bf16_rne(a), hc = bf16_rne(c);
                ushort la = bf16_rne(a - bf16f(ha)), lc = bf16_rne(c - bf16f(hc));
                hp[j2] = (uint)ha | ((uint)hc << 16);
                lp[j2] = (uint)la | ((uint)lc << 16);
            }
            const int slot = (u ^ (p & 7)) * 16;
            *(uint4*)(smem + p * 128 + slot) = make_uint4(hp[0], hp[1], hp[2], hp[3]);
            *(uint4*)(smem + 16384 + p * 128 + slot) = make_uint4(lp[0], lp[1], lp[2], lp[3]);
        }
    }
    __syncthreads();

    const int lane = tid & 63, w = tid >> 6;
    const int m = lane & 15, quad = lane >> 4;

    // ---- A fragments (2 point-tiles x 2 K-steps, hi+lo) in regs for the whole kernel
    short8 Ah[2][2], Al[2][2];
    #pragma unroll
    for (int pt = 0; pt < 2; ++pt) {
        const int p = w * 32 + pt * 16 + m;
        #pragma unroll
        for (int ks = 0; ks < 2; ++ks) {
            const int u = ks * 4 + quad;
            const int a = p * 128 + ((u ^ (p & 7)) * 16);
            Ah[pt][ks] = *(const short8*)(smem + a);
            Al[pt][ks] = *(const short8*)(smem + 16384 + a);
        }
    }
    __syncthreads();   // X LDS dead for ALL waves beyond this point (epilogue may overlay)

    float v1s[8], v2s[8]; int i1s[8];
    #pragma unroll
    for (int s = 0; s < 8; ++s) { v1s[s] = 1e30f; v2s[s] = 1e30f; i1s[s] = 0; }

    // ---- barrier-free K-loop: B frags straight from global (L1-hot 256 KB table)
    #pragma unroll 2
    for (int ch = 0; ch < 16; ++ch) {
        const int kb0 = ch * 64;
        #pragma unroll
        for (int np = 0; np < 2; ++np) {
            const int ca = kb0 + np * 32 + m, cb = ca + 16;   // absolute code ids
            short8 BhA[2], BlA[2], BhB[2], BlB[2];
            #pragma unroll
            for (int ks = 0; ks < 2; ++ks) {
                const size_t ua = (size_t)ca * 64 + (ks * 4 + quad) * 8;
                const size_t ub = (size_t)cb * 64 + (ks * 4 + quad) * 8;
                BhA[ks] = *(const short8*)(Ehw + ua);
                BlA[ks] = *(const short8*)(Elw + ua);
                BhB[ks] = *(const short8*)(Ehw + ub);
                BlB[ks] = *(const short8*)(Elw + ub);
            }
            const float ha = hsqw[ca], hb = hsqw[cb];
            #pragma unroll
            for (int pt = 0; pt < 2; ++pt) {
                f32x4 aA = {0.f, 0.f, 0.f, 0.f}, aB = {0.f, 0.f, 0.f, 0.f};
                aA = __builtin_amdgcn_mfma_f32_16x16x32_bf16(Ah[pt][0], BhA[0], aA, 0, 0, 0);
                aB = __builtin_amdgcn_mfma_f32_16x16x32_bf16(Ah[pt][0], BhB[0], aB, 0, 0, 0);
                aA = __builtin_amdgcn_mfma_f32_16x16x32_bf16(Ah[pt][1], BhA[1], aA, 0, 0, 0);
                aB = __builtin_amdgcn_mfma_f32_16x16x32_bf16(Ah[pt][1], BhB[1], aB, 0, 0, 0);
                aA = __builtin_amdgcn_mfma_f32_16x16x32_bf16(Ah[pt][0], BlA[0], aA, 0, 0, 0);
                aB = __builtin_amdgcn_mfma_f32_16x16x32_bf16(Ah[pt][0], BlB[0], aB, 0, 0, 0);
                aA = __builtin_amdgcn_mfma_f32_16x16x32_bf16(Ah[pt][1], BlA[1], aA, 0, 0, 0);
                aB = __builtin_amdgcn_mfma_f32_16x16x32_bf16(Ah[pt][1], BlB[1], aB, 0, 0, 0);
                aA = __builtin_amdgcn_mfma_f32_16x16x32_bf16(Al[pt][0], BhA[0], aA, 0, 0, 0);
                aB = __builtin_amdgcn_mfma_f32_16x16x32_bf16(Al[pt][0], BhB[0], aB, 0, 0, 0);
                aA = __builtin_amdgcn_mfma_f32_16x16x32_bf16(Al[pt][1], BhA[1], aA, 0, 0, 0);
                aB = __builtin_amdgcn_mfma_f32_16x16x32_bf16(Al[pt][1], BhB[1], aB, 0, 0, 0);
                #pragma unroll
                for (int r = 0; r < 4; ++r) {
                    const int s = pt * 4 + r;
                    float va = ha - aA[r], vb = hb - aB[r];
                    float lo = fminf(va, vb), hi = fmaxf(va, vb);
                    int ip = (vb < va) ? cb : ca;           // tie -> lower code
                    v2s[s] = fminf(v2s[s], hi);             // exact 2nd-min: pair partner
                    v2s[s] = fminf(v2s[s], fmaxf(lo, v1s[s]));
                    bool c = lo < v1s[s];                   // strict: keeps first (lowest) idx
                    i1s[s] = c ? ip : i1s[s];
                    v1s[s] = fminf(lo, v1s[s]);
                }
            }
        }
    }

    // ---- merge states across the 16 code-columns (xor shuffle in 16-lane groups)
    #pragma unroll
    for (int st = 1; st < 16; st <<= 1) {
        #pragma unroll
        for (int s = 0; s < 8; ++s) {
            float ov1 = __shfl_xor(v1s[s], st);
            float ov2 = __shfl_xor(v2s[s], st);
            int   oi1 = __shfl_xor(i1s[s], st);
            v2s[s] = fminf(fminf(v2s[s], ov2), fmaxf(v1s[s], ov1));
            bool c = (ov1 < v1s[s]) || (ov1 == v1s[s] && oi1 < i1s[s]);
            if (c) i1s[s] = oi1;
            v1s[s] = fminf(v1s[s], ov1);
        }
    }

    // epilogue scratch overlays dead X region
    float* pv1 = (float*)smem;                         // [128]
    int*   pi1 = (int*)(smem + 512);                   // [128]
    float* pv2 = (float*)(smem + 1024);                // [128]
    ull*   msk = (ull*)(smem + 1536);                  // [2]
    int*   lst = (int*)(smem + 1568);                  // [0]=cnt, entries at +1

    if (m == 0) {
        #pragma unroll
        for (int s = 0; s < 8; ++s) {
            int p = w * 32 + (s >> 2) * 16 + quad * 4 + (s & 3);
            pv1[p] = v1s[s]; pi1[p] = i1s[s]; pv2[p] = v2s[s];
        }
    }
    __syncthreads();

    // ---- flag near-ties via ballot (waves 0,1 cover points 0..127)
    {
        bool f = (tid < NPB) && ((pv2[tid] - pv1[tid]) < EPSGAP);
        ull bm = __ballot(f);
        if (lane == 0 && w < 2) msk[w] = bm;
    }
    __syncthreads();
    if (tid == 0) {
        int c = 0;
        ull m0 = msk[0];
        while (m0) { int i = __ffsll(m0) - 1; lst[1 + c++] = i; m0 &= m0 - 1; }
        ull m1 = msk[1];
        while (m1) { int i = __ffsll(m1) - 1; lst[1 + c++] = 64 + i; m1 &= m1 - 1; }
        lst[0] = c;
    }
    __syncthreads();

    // ---- exact fp32 rescan, one wave per flagged point (rare: gap<1e-3)
    const int cnt = lst[0];
    for (int it = w; it < cnt; it += 4) {
        const int p = lst[1 + it];
        float xv = xbase[lane * HW + p];               // lane d holds x_d (exact fp32)
        float acc[16];
        #pragma unroll
        for (int j = 0; j < 16; ++j) acc[j] = 0.f;
        #pragma unroll 4
        for (int d4 = 0; d4 < 16; ++d4) {
            float x0 = __shfl(xv, d4 * 4 + 0), x1 = __shfl(xv, d4 * 4 + 1);
            float x2 = __shfl(xv, d4 * 4 + 2), x3 = __shfl(xv, d4 * 4 + 3);
            #pragma unroll
            for (int j = 0; j < 16; ++j) {
                const int k = lane + 64 * j;
                float4 e = *(const float4*)(emb + (size_t)k * DIMS + d4 * 4);
                acc[j] = fmaf(x0, e.x, acc[j]); acc[j] = fmaf(x1, e.y, acc[j]);
                acc[j] = fmaf(x2, e.z, acc[j]); acc[j] = fmaf(x3, e.w, acc[j]);
            }
        }
        float bv = 1e30f; int bk = 0;
        #pragma unroll
        for (int j = 0; j < 16; ++j) {                 // ascending k per lane: first-min kept
            const int k = lane + 64 * j;
            float v = hsqw[k] - acc[j];
            if (v < bv) { bv = v; bk = k; }
        }
        #pragma unroll
        for (int st = 32; st; st >>= 1) {              // 64-wide (v, k) argmin, k tie-break
            float ov = __shfl_xor(bv, st);
            int   ok = __shfl_xor(bk, st);
            if (ov < bv || (ov == bv && ok < bk)) { bv = ov; bk = ok; }
        }
        if (lane == 0) pi1[p] = bk;
    }
    __syncthreads();

    // ---- final: indices, quantized gather-write, loss (waves 0,1)
    if (tid < NPB) {
        const int p = tid;
        const int bi = pi1[p];
        out[IOFF + n0 + p] = (float)bi;
        const float* e = emb + (size_t)bi * DIMS;
        const float* xp = xbase + p;
        float* oq = out + QOFF + (size_t)b * (DIMS * HW) + off + p;
        float ls = 0.f;
        #pragma unroll 8
        for (int d = 0; d < DIMS; ++d) {
            float ev = e[d];
            float xv = xp[d * HW];
            float df = ev - xv;
            ls = fmaf(df, df, ls);
            oq[d * HW] = ev;                           // coalesced across point-threads
        }
        #pragma unroll
        for (int st = 32; st; st >>= 1) ls += __shfl_down(ls, st);
        if (lane == 0) atomicAdd(out, ls * (0.25f / (float)(NPTS * DIMS)));
    }
}

extern "C" void kernel_launch(void* const* d_in, const int* in_sizes, int n_in,
                              void* d_out, int out_size, void* d_ws, size_t ws_size,
                              hipStream_t stream) {
    const float* in  = (const float*)d_in[0];
    const float* emb = (const float*)d_in[1];
    float* out = (float*)d_out;
    ushort* Eh = (ushort*)d_ws;                        // 131072 B
    ushort* El = (ushort*)((char*)d_ws + 131072);      // 131072 B
    float*  hsq = (float*)((char*)d_ws + 262144);      // 4096 B
    (void)in_sizes; (void)n_in; (void)out_size; (void)ws_size;

    vq_prep<<<64, 256, 0, stream>>>(emb, Eh, El, hsq, out);   // also zeroes out[0]
    vq_main<<<NPTS / NPB, 256, 0, stream>>>(in, emb, Eh, El, hsq, out);
}